// Round 2
// baseline (127.766 us; speedup 1.0000x reference)
//
#include <hip/hip_runtime.h>
#include <hip/hip_bf16.h>

#define NN   1024
#define FIN  128
#define FOUT 64

typedef __attribute__((ext_vector_type(8))) short short8;
typedef __attribute__((ext_vector_type(4))) float f32x4;

__device__ inline unsigned short f2bf(float x) {
    union { __hip_bfloat16 h; unsigned short u; } c;
    c.h = __float2bfloat16(x);
    return c.u;
}
__device__ inline unsigned packbf(float a, float b) {
    return (unsigned)f2bf(a) | ((unsigned)f2bf(b) << 16);
}

// ---------------- Kernel 1: Wh = X @ W (fp32), s1/s2 row scores, Wh^T bf16 out
__global__ __launch_bounds__(256) void k1_proj(
    const float* __restrict__ X, const float* __restrict__ W,
    const float* __restrict__ a,
    unsigned short* __restrict__ whbt,   // [B][FOUT][NN] bf16
    float* __restrict__ s1g, float* __restrict__ s2g)
{
    __shared__ float Ws[FIN][FOUT];        // 32KB
    __shared__ float Xs[64][FIN + 4];
    __shared__ unsigned short Ob[FOUT][64];

    const int t = threadIdx.x;
    const int blk = blockIdx.x;            // 1024 blocks
    const int b = blk >> 4;
    const int r0 = (blk & 15) << 6;        // 64 rows per block
    const float* Xg = X + ((size_t)(b * NN + r0)) * FIN;

    const float4* Wg4 = (const float4*)W;
    #pragma unroll
    for (int i = 0; i < 8; ++i) {
        int idx = t + i * 256;
        float4 v = Wg4[idx];
        int kk = idx >> 4, oo = (idx & 15) << 2;
        *(float4*)&Ws[kk][oo] = v;
    }
    #pragma unroll
    for (int i = 0; i < 8; ++i) {
        int idx = t + i * 256;
        float4 v = ((const float4*)Xg)[idx];
        int rr = idx >> 5, cc = (idx & 31) << 2;
        *(float4*)&Xs[rr][cc] = v;
    }
    __syncthreads();

    const int l = t & 63, w = t >> 6;
    const int c0 = (l & 15) << 2;
    const int rs = l >> 4;
    const int rbase = w * 16 + rs * 4;

    float acc[4][4] = {};
    for (int k = 0; k < FIN; ++k) {
        float4 wv = *(const float4*)&Ws[k][c0];
        #pragma unroll
        for (int q = 0; q < 4; ++q) {
            float x = Xs[rbase + q][k];
            acc[q][0] += x * wv.x; acc[q][1] += x * wv.y;
            acc[q][2] += x * wv.z; acc[q][3] += x * wv.w;
        }
    }

    float a1v[4], a2v[4];
    #pragma unroll
    for (int c = 0; c < 4; ++c) { a1v[c] = a[c0 + c]; a2v[c] = a[FOUT + c0 + c]; }
    #pragma unroll
    for (int q = 0; q < 4; ++q) {
        float p1 = acc[q][0]*a1v[0] + acc[q][1]*a1v[1] + acc[q][2]*a1v[2] + acc[q][3]*a1v[3];
        float p2 = acc[q][0]*a2v[0] + acc[q][1]*a2v[1] + acc[q][2]*a2v[2] + acc[q][3]*a2v[3];
        #pragma unroll
        for (int m = 1; m <= 8; m <<= 1) {
            p1 += __shfl_xor(p1, m, 64);
            p2 += __shfl_xor(p2, m, 64);
        }
        if ((l & 15) == 0) {
            int row = r0 + rbase + q;
            s1g[b * NN + row] = p1;
            s2g[b * NN + row] = p2;
        }
    }

    #pragma unroll
    for (int q = 0; q < 4; ++q)
        #pragma unroll
        for (int c = 0; c < 4; ++c)
            Ob[c0 + c][rbase + q] = f2bf(acc[q][c]);
    __syncthreads();

    {
        int o = t >> 2, rseg = (t & 3) << 4;
        unsigned short* dst = whbt + ((size_t)(b * FOUT + o)) * NN + r0 + rseg;
        const unsigned short* sp = &Ob[o][rseg];
        *(float4*)dst       = *(const float4*)sp;
        *(float4*)(dst + 8) = *(const float4*)(sp + 8);
    }
}

// ---------------- Kernel 1b: s2max per batch
__global__ __launch_bounds__(256) void k1b_max(
    const float* __restrict__ s2g, float* __restrict__ s2max)
{
    int b = blockIdx.x, t = threadIdx.x;
    float m = -3.4e38f;
    #pragma unroll
    for (int i = 0; i < 4; ++i) m = fmaxf(m, s2g[b * NN + t + i * 256]);
    #pragma unroll
    for (int d = 1; d <= 32; d <<= 1) m = fmaxf(m, __shfl_xor(m, d, 64));
    __shared__ float red[4];
    if ((t & 63) == 0) red[t >> 6] = m;
    __syncthreads();
    if (t == 0) s2max[b] = fmaxf(fmaxf(red[0], red[1]), fmaxf(red[2], red[3]));
}

// ---------------- Kernel 2: barrier-free fused softmax + P@Wh, P built
// directly in MFMA A-fragment layout (lane = row l&15, j = (l>>4)*8..+7).
__global__ __launch_bounds__(256) void k2_attn(
    const int* __restrict__ adj,
    const unsigned short* __restrict__ whbt,
    const float* __restrict__ s1g, const float* __restrict__ s2g,
    const float* __restrict__ s2maxg,
    float* __restrict__ outg)
{
    const int t = threadIdx.x, l = t & 63, w = t >> 6;
    const int bid = blockIdx.x;            // 1024 blocks
    const int b = bid >> 4;
    const int i0 = (bid & 15) << 6;        // 64 rows/block, 16 rows/wave
    const int r16 = l & 15;
    const int jo = (l >> 4) << 3;          // lane's j-offset within 32-j slice
    const int row = i0 + w * 16 + r16;

    const float s2m = s2maxg[b];
    const float s1v = s1g[b * NN + row];
    const float tt = s1v + s2m;
    const float Mr = fmaxf(tt, 0.1f * tt); // exact upper bound on row max (leaky monotone)

    const int* adjr = adj + (size_t)b * NN * NN + (size_t)row * NN;
    const float* s2r = s2g + b * NN;
    const unsigned short* wb = whbt + (size_t)b * FOUT * NN + (size_t)r16 * NN;

    f32x4 acc[4];
    #pragma unroll
    for (int s = 0; s < 4; ++s)
        #pragma unroll
        for (int r = 0; r < 4; ++r) acc[s][r] = 0.f;
    float den = 0.f;

    #pragma unroll 2
    for (int jt = 0; jt < NN; jt += 32) {
        const int j0 = jt + jo;
        int4 a0 = *(const int4*)(adjr + j0);
        int4 a1 = *(const int4*)(adjr + j0 + 4);
        float4 sa = *(const float4*)(s2r + j0);
        float4 sb = *(const float4*)(s2r + j0 + 4);
        short8 bf[4];
        #pragma unroll
        for (int s = 0; s < 4; ++s)
            bf[s] = *(const short8*)(wb + (size_t)s * (16 * NN) + j0);

        const float sv[8] = {sa.x, sa.y, sa.z, sa.w, sb.x, sb.y, sb.z, sb.w};
        const int   am[8] = {a0.x, a0.y, a0.z, a0.w, a1.x, a1.y, a1.z, a1.w};
        unsigned pk[4];
        #pragma unroll
        for (int e = 0; e < 4; ++e) {
            float xa = s1v + sv[2*e];
            float xb = s1v + sv[2*e+1];
            float ea = fmaxf(xa, 0.1f * xa) - Mr;
            float eb = fmaxf(xb, 0.1f * xb) - Mr;
            float pa = am[2*e]   > 0 ? __expf(ea) : 0.f;
            float pb = am[2*e+1] > 0 ? __expf(eb) : 0.f;
            den += pa + pb;
            pk[e] = packbf(pa, pb);
        }
        union { unsigned u[4]; short8 s8; } A;
        A.u[0] = pk[0]; A.u[1] = pk[1]; A.u[2] = pk[2]; A.u[3] = pk[3];
        #pragma unroll
        for (int s = 0; s < 4; ++s)
            acc[s] = __builtin_amdgcn_mfma_f32_16x16x32_bf16(A.s8, bf[s], acc[s], 0, 0, 0);
    }

    // row denominator: lanes {l, l^16, l^32, l^48} share row r16
    den += __shfl_xor(den, 16, 64);
    den += __shfl_xor(den, 32, 64);

    // D layout: row = (l>>4)*4 + rr, col = s*16 + r16
    const int rb = (l >> 4) << 2;
    float inv[4];
    #pragma unroll
    for (int rr = 0; rr < 4; ++rr) {
        float dd = __shfl(den, rb + rr, 64);   // lane rb+rr holds den of row rb+rr
        inv[rr] = dd > 0.f ? 1.f / dd : 0.f;
    }
    float* orow = outg + ((size_t)(b * NN + i0 + w * 16 + rb)) * FOUT;
    #pragma unroll
    for (int s = 0; s < 4; ++s)
        #pragma unroll
        for (int rr = 0; rr < 4; ++rr) {
            float v = acc[s][rr] * inv[rr];
            float res = v > 0.f ? v : (__expf(v) - 1.f);
            orow[(size_t)rr * FOUT + s * 16 + r16] = res;
        }
}

extern "C" void kernel_launch(void* const* d_in, const int* in_sizes, int n_in,
                              void* d_out, int out_size, void* d_ws, size_t ws_size,
                              hipStream_t stream) {
    const float* atoms = (const float*)d_in[0];
    const int*   adj   = (const int*)d_in[1];
    const float* W     = (const float*)d_in[2];
    const float* a     = (const float*)d_in[3];
    float* out = (float*)d_out;

    unsigned short* whbt = (unsigned short*)d_ws;                       // 8 MB bf16
    float* s1g    = (float*)((char*)d_ws + (8u << 20));                 // 256 KB
    float* s2g    = (float*)((char*)d_ws + (8u << 20) + (256u << 10));  // 256 KB
    float* s2maxg = (float*)((char*)d_ws + (8u << 20) + (512u << 10));  // 256 B

    k1_proj<<<1024, 256, 0, stream>>>(atoms, W, a, whbt, s1g, s2g);
    k1b_max<<<64, 256, 0, stream>>>(s2g, s2maxg);
    k2_attn<<<1024, 256, 0, stream>>>(adj, whbt, s1g, s2g, s2maxg, out);
}